// Round 8
// baseline (88.051 us; speedup 1.0000x reference)
//
#include <hip/hip_runtime.h>

// DBSCAN neighbor-count + classify via augmented-K bf16 MFMA, MI355X (gfx950)
// B=4, N=8192, D=16 fp32 in, int32 out.
// dist(i,j) < EPS=0.5  <=>  x_i.x_j - g_i - g_j > 0,  g_p = 0.5*||x_p||^2 - EPS^2/4
// Augmented 32-K lane layout for mfma_f32_16x16x32_bf16 with zero C:
//   A row i: k0..15 = x_i, k16..17 = [-g_i, 1], k18..31 = 0
//   B col j: k0..15 = x_j, k16..17 = [1, -g_j], k18..31 = 0
// out[p] = (count_p < 10) ? -1 : 0
//
// R8: RF 4->8 (128 i-rows/wave), prefetch depth 2. Budget re-fit across
// R2-R7 pins count at ~31-35us (~5x the 7us VALU floor) with occupancy/
// B-path/atomic/dispatch theories all falsified -> excess is per-tile fixed
// cost (ds_read wait, loop, MFMA-issue turnaround). Halve tile-instances,
// keep per-pair epilogue (the true floor) unchanged.

constexpr int Np = 8192;
constexpr int Bb = 4;
constexpr int MIN_PTS = 10;
constexpr float EPS2_4 = 0.0625f;  // EPS^2 / 4
constexpr int JS = 16;         // j-windows per batch
constexpr int JW = Np / JS;    // 512 j per window/block
constexpr int ICH = 512;       // i rows per block (4 waves x 128)
constexpr int RF = 8;          // A fragments per wave (16 rows each)
constexpr int NT = JW / 16;    // 32 j-tiles per window

typedef __bf16 bf16x8 __attribute__((ext_vector_type(8)));
typedef float  f32x4  __attribute__((ext_vector_type(4)));

// ---------------- count: fused convert+stage, LDS Gram sweep ----------------
// grid: 4 b x 16 i-chunks x 16 j-windows = 1024 blocks, 256 threads (4 waves).
// 4 blocks/CU (LDS 24.6 KB), 4 waves/SIMD.
__global__ __launch_bounds__(256, 4)
void dbscan_count(const float* __restrict__ x, int* __restrict__ part) {
    const int lane = threadIdx.x & 63;
    const int w    = threadIdx.x >> 6;
    const int m    = lane & 15;          // A/B row-col within tile
    const int q    = lane >> 4;          // k-chunk; C row group
    const int blk  = blockIdx.x;
    const int b    = blk >> 8;
    const int ic   = (blk >> 4) & 15;
    const int js   = blk & 15;
    const size_t pbase = (size_t)b * Np;
    const int ibase = ic * ICH;
    const int jbase = js * JW;

    // LDS: [tile][slot], slot = r*16 + (p&15), r=0,1 features, r=2 augment. 24.6 KB.
    __shared__ __bf16 ldsB[NT * 48 * 8];

    // Stage j-window: 2 points per thread, fp32 -> bf16 + augment, frag order.
    {
        const float* xw = x + (pbase + jbase) * 16;
#pragma unroll
        for (int it = 0; it < 2; it++) {
            const int p = threadIdx.x + it * 256;
            const float4* src = (const float4*)(xw + (size_t)p * 16);
            float4 v0 = src[0], v1 = src[1], v2 = src[2], v3 = src[3];
            float vv[16];
            vv[0]=v0.x; vv[1]=v0.y; vv[2]=v0.z; vv[3]=v0.w;
            vv[4]=v1.x; vv[5]=v1.y; vv[6]=v1.z; vv[7]=v1.w;
            vv[8]=v2.x; vv[9]=v2.y; vv[10]=v2.z; vv[11]=v2.w;
            vv[12]=v3.x; vv[13]=v3.y; vv[14]=v3.z; vv[15]=v3.w;
            float s = 0.f;
#pragma unroll
            for (int k = 0; k < 16; k++) s = fmaf(vv[k], vv[k], s);
            const float g = 0.5f * s - EPS2_4;
            bf16x8 h0, h1, h2;
#pragma unroll
            for (int k = 0; k < 8; k++) { h0[k] = (__bf16)vv[k]; h1[k] = (__bf16)vv[k+8]; }
            h2[0] = (__bf16)1.0f; h2[1] = (__bf16)(-g);
#pragma unroll
            for (int k = 2; k < 8; k++) h2[k] = (__bf16)0.0f;
            const int base = (p >> 4) * 48 + (p & 15);
            *(bf16x8*)(ldsB + (size_t)(base     ) * 8) = h0;
            *(bf16x8*)(ldsB + (size_t)(base + 16) * 8) = h1;
            *(bf16x8*)(ldsB + (size_t)(base + 32) * 8) = h2;
        }
    }

    // A fragments: inline convert from fp32 rows (one-time, L2-resident reads).
    bf16x8 af[RF];
#pragma unroll
    for (int f = 0; f < RF; f++) {
        const float4* ap = (const float4*)(x + (pbase + ibase + w * 128 + f * 16 + m) * 16);
        float4 u0 = ap[0], u1 = ap[1], u2 = ap[2], u3 = ap[3];
        float uu[16];
        uu[0]=u0.x; uu[1]=u0.y; uu[2]=u0.z; uu[3]=u0.w;
        uu[4]=u1.x; uu[5]=u1.y; uu[6]=u1.z; uu[7]=u1.w;
        uu[8]=u2.x; uu[9]=u2.y; uu[10]=u2.z; uu[11]=u2.w;
        uu[12]=u3.x; uu[13]=u3.y; uu[14]=u3.z; uu[15]=u3.w;
        float s = 0.f;
#pragma unroll
        for (int k = 0; k < 16; k++) s = fmaf(uu[k], uu[k], s);
        const float g = 0.5f * s - EPS2_4;
        bf16x8 a;
        if (q == 0) {
#pragma unroll
            for (int k = 0; k < 8; k++) a[k] = (__bf16)uu[k];
        } else if (q == 1) {
#pragma unroll
            for (int k = 0; k < 8; k++) a[k] = (__bf16)uu[k + 8];
        } else if (q == 2) {
            a[0] = (__bf16)(-g); a[1] = (__bf16)1.0f;
#pragma unroll
            for (int k = 2; k < 8; k++) a[k] = (__bf16)0.0f;
        } else {
#pragma unroll
            for (int k = 0; k < 8; k++) a[k] = (__bf16)0.0f;
        }
        af[f] = a;
    }

    __syncthreads();

    // B fragment address: q<3 -> slot q*16+m; q==3 -> broadcast slot 0 (dead input)
    const __bf16* bptr = ldsB + (q < 3 ? (q * 16 + m) * 8 : 0);

    const f32x4 zacc = {0.f, 0.f, 0.f, 0.f};
    int cnt[RF * 4];
#pragma unroll
    for (int i = 0; i < RF * 4; i++) cnt[i] = 0;

    // Depth-2 prefetch: wait before MFMA covers a load issued 2 tiles back.
    bf16x8 bq0 = *(const bf16x8*)bptr;
    bf16x8 bq1 = *(const bf16x8*)(bptr + 48 * 8);
#pragma unroll 2
    for (int t = 0; t < NT; t++) {
        bf16x8 cur = (t & 1) ? bq1 : bq0;
        const int tn = (t + 2) & (NT - 1);
        bf16x8 nxt = *(const bf16x8*)(bptr + tn * 48 * 8);
        if (t & 1) bq1 = nxt; else bq0 = nxt;
#pragma unroll
        for (int f = 0; f < RF; f++) {
            f32x4 acc = __builtin_amdgcn_mfma_f32_16x16x32_bf16(af[f], cur, zacc, 0, 0, 0);
            cnt[f*4+0] += (acc[0] > 0.0f) ? 1 : 0;
            cnt[f*4+1] += (acc[1] > 0.0f) ? 1 : 0;
            cnt[f*4+2] += (acc[2] > 0.0f) ? 1 : 0;
            cnt[f*4+3] += (acc[3] > 0.0f) ? 1 : 0;
        }
    }

    // Sum across the 16 cols (lane bits 0..3); lane m==0 of each q stores rows.
#pragma unroll
    for (int i = 0; i < RF * 4; i++) {
        int v = cnt[i];
        v += __shfl_xor(v, 1);
        v += __shfl_xor(v, 2);
        v += __shfl_xor(v, 4);
        v += __shfl_xor(v, 8);
        cnt[i] = v;
    }
    if (m == 0) {
        // partials layout: part[row_global][js], 16 ints (64 B) per row
        int* pb = part + ((pbase + ibase + w * 128) * 16) + js;
#pragma unroll
        for (int f = 0; f < RF; f++)
#pragma unroll
            for (int r = 0; r < 4; r++)
                pb[(size_t)(f * 16 + q * 4 + r) * 16] = cnt[f*4+r];
    }
}

// ---------------- reduce + classify -----------------------------------------
__global__ __launch_bounds__(256)
void dbscan_reduce(const int* __restrict__ part, int* __restrict__ out) {
    const int row = blockIdx.x * 256 + threadIdx.x;   // 32768 rows
    const int4* p = (const int4*)(part + (size_t)row * 16);
    int4 a = p[0], b = p[1], c = p[2], d = p[3];
    int s = a.x + a.y + a.z + a.w + b.x + b.y + b.z + b.w
          + c.x + c.y + c.z + c.w + d.x + d.y + d.z + d.w;
    out[row] = (s < MIN_PTS) ? -1 : 0;
}

extern "C" void kernel_launch(void* const* d_in, const int* in_sizes, int n_in,
                              void* d_out, int out_size, void* d_ws, size_t ws_size,
                              hipStream_t stream) {
    const float* x = (const float*)d_in[0];
    int* out = (int*)d_out;
    int* part = (int*)d_ws;    // 32768 * 16 * 4 B = 2 MB

    dbscan_count<<<dim3(Bb * 16 * JS), dim3(256), 0, stream>>>(x, part);
    dbscan_reduce<<<dim3(Bb * Np / 256), dim3(256), 0, stream>>>(part, out);
}

// Round 9
// 76.395 us; speedup vs baseline: 1.1526x; 1.1526x over previous
//
#include <hip/hip_runtime.h>

// DBSCAN neighbor-count + classify via augmented-K bf16 MFMA, MI355X (gfx950)
// B=4, N=8192, D=16 fp32 in, int32 out.
// dist(i,j) < EPS=0.5  <=>  x_i.x_j - g_i - g_j > 0,  g_p = 0.5*||x_p||^2 - EPS^2/4
// Augmented point (24 bf16 = 48 B): [x0..x15, 1.0, -g, 0...]
//   A row i swaps k16..17 to [-g_i, 1]; B col j supplies [1, -g_j]
//   => mfma_f32_16x16x32_bf16 with zero C emits x_i.x_j - g_i - g_j directly.
// out[p] = (count_p < 10) ? -1 : 0
//
// R9 = R5 (best, 80.7us) + ONE change: epilogue predicate-add replaced by the
// sign-bit trick  cnt += float_as_int(acc)>>31  (accumulates -#neg; count =
// 512 + sum per window). Removes the vcc serialization of v_cmp+v_addc —
// 16 independent 2-inst chains per tile. Tests the dependency-chain theory
// for the 29us-vs-9us-model gap; all structural theories (occupancy, B-path,
// atomics, dispatch count, RF) are falsified by R3-R8.

constexpr int Np = 8192;
constexpr int Bb = 4;
constexpr int MIN_PTS = 10;
constexpr float EPS2_4 = 0.0625f;  // EPS^2 / 4
constexpr int JS = 16;         // j-windows per batch
constexpr int JW = Np / JS;    // 512 j per window/block
constexpr int ICH = 256;       // i rows per block (4 waves x 64)
constexpr int RF = 4;          // A fragments per wave (16 rows each)
constexpr int NT = JW / 16;    // 32 j-tiles per window

typedef __bf16 bf16x8 __attribute__((ext_vector_type(8)));
typedef float  f32x4  __attribute__((ext_vector_type(4)));

// ---------------- prep: fp32 -> augmented bf16; zero the count buffer -------
__global__ __launch_bounds__(256)
void dbscan_prep(const float* __restrict__ x, __bf16* __restrict__ aug,
                 int* __restrict__ out) {
    const int p = blockIdx.x * 256 + threadIdx.x;    // 32768 points
    const float4* src = (const float4*)(x + (size_t)p * 16);
    float4 v0 = src[0], v1 = src[1], v2 = src[2], v3 = src[3];
    float vv[16];
    vv[0]=v0.x; vv[1]=v0.y; vv[2]=v0.z; vv[3]=v0.w;
    vv[4]=v1.x; vv[5]=v1.y; vv[6]=v1.z; vv[7]=v1.w;
    vv[8]=v2.x; vv[9]=v2.y; vv[10]=v2.z; vv[11]=v2.w;
    vv[12]=v3.x; vv[13]=v3.y; vv[14]=v3.z; vv[15]=v3.w;
    float s = 0.f;
#pragma unroll
    for (int k = 0; k < 16; k++) s = fmaf(vv[k], vv[k], s);
    const float g = 0.5f * s - EPS2_4;
    bf16x8 h0, h1, h2;
#pragma unroll
    for (int k = 0; k < 8; k++) { h0[k] = (__bf16)vv[k]; h1[k] = (__bf16)vv[k+8]; }
    h2[0] = (__bf16)1.0f; h2[1] = (__bf16)(-g);
#pragma unroll
    for (int k = 2; k < 8; k++) h2[k] = (__bf16)0.0f;
    bf16x8* dst = (bf16x8*)(aug + (size_t)p * 24);
    dst[0] = h0; dst[1] = h1; dst[2] = h2;
    out[p] = 0;
}

// ---------------- count: LDS-staged Gram sweep, atomicAdd partials ----------
// grid: 4 b x 32 i-chunks x 16 j-windows = 2048 blocks, 256 threads.
__global__ __launch_bounds__(256, 6)
void dbscan_count(const __bf16* __restrict__ aug, int* __restrict__ out) {
    const int lane = threadIdx.x & 63;
    const int w    = threadIdx.x >> 6;
    const int m    = lane & 15;          // A/B row-col within tile
    const int q    = lane >> 4;          // k-chunk; C row group
    const int blk  = blockIdx.x;
    const int b    = blk >> 9;
    const int ic   = (blk >> 4) & 31;
    const int js   = blk & 15;
    const size_t pbase = (size_t)b * Np;
    const int ibase = ic * ICH;
    const int jbase = js * JW;

    // LDS: [tile][slot], slot = r*16 + (p&15), 8 bf16 per slot. 24.6 KB.
    __shared__ __bf16 ldsB[NT * 48 * 8];

    // Stage window: 1536 16B-chunks; chunk c = point p=c/3, piece r=c%3.
    {
        const __bf16* src = aug + (pbase + jbase) * 24;
#pragma unroll
        for (int it = 0; it < 6; it++) {
            const int c = threadIdx.x + it * 256;
            const int p = c / 3;
            const int r = c - p * 3;
            bf16x8 v = *(const bf16x8*)(src + (size_t)c * 8);
            *(bf16x8*)(ldsB + (((p >> 4) * 48) + r * 16 + (p & 15)) * 8) = v;
        }
    }

    // A fragments (global, loop-invariant). Rows: ibase+w*64+f*16+m.
    bf16x8 af[RF];
#pragma unroll
    for (int f = 0; f < RF; f++) {
        const __bf16* ap = aug + (pbase + ibase + w * 64 + f * 16 + m) * 24 + q * 8;
        bf16x8 a = *(const bf16x8*)ap;     // q=3 overreads next point; zeroed below
        if (q == 2) { __bf16 t = a[0]; a[0] = a[1]; a[1] = t; }   // [1,-g] -> [-g,1]
        if (q == 3) {
#pragma unroll
            for (int k = 0; k < 8; k++) a[k] = (__bf16)0.0f;
        }
        af[f] = a;
    }

    __syncthreads();

    // B fragment address: q<3 -> slot q*16+m; q==3 -> broadcast slot 0 (dead input)
    const __bf16* bptr = ldsB + (q < 3 ? (q * 16 + m) * 8 : 0);

    const f32x4 zacc = {0.f, 0.f, 0.f, 0.f};
    int cnt[16];
#pragma unroll
    for (int i = 0; i < 16; i++) cnt[i] = 0;

    bf16x8 bc = *(const bf16x8*)bptr;
#pragma unroll 2
    for (int t = 0; t < NT; t++) {
        const int tn = (t + 1) & (NT - 1);
        bf16x8 bn = *(const bf16x8*)(bptr + tn * 48 * 8);   // depth-1 prefetch
#pragma unroll
        for (int f = 0; f < RF; f++) {
            f32x4 acc = __builtin_amdgcn_mfma_f32_16x16x32_bf16(af[f], bc, zacc, 0, 0, 0);
            // sign-bit accumulate: adds -1 per NEGATIVE result (no vcc chain).
            cnt[f*4+0] += __float_as_int(acc[0]) >> 31;
            cnt[f*4+1] += __float_as_int(acc[1]) >> 31;
            cnt[f*4+2] += __float_as_int(acc[2]) >> 31;
            cnt[f*4+3] += __float_as_int(acc[3]) >> 31;
        }
        bc = bn;
    }

    // Sum across the 16 cols (lane bits 0..3); lane m==0 of each q adds rows.
    // Each row saw JW results total -> count_pos = JW + sum(negatives).
#pragma unroll
    for (int i = 0; i < 16; i++) {
        int v = cnt[i];
        v += __shfl_xor(v, 1);
        v += __shfl_xor(v, 2);
        v += __shfl_xor(v, 4);
        v += __shfl_xor(v, 8);
        cnt[i] = v;
    }
    if (m == 0) {
        int* ob = out + pbase + ibase + w * 64;
#pragma unroll
        for (int f = 0; f < RF; f++)
#pragma unroll
            for (int r = 0; r < 4; r++)
                atomicAdd(&ob[f*16 + q*4 + r], JW + cnt[f*4+r]);
    }
}

// ---------------- classify ----------------
__global__ __launch_bounds__(256)
void dbscan_classify(int* __restrict__ out) {
    const int p = blockIdx.x * 256 + threadIdx.x;
    out[p] = (out[p] < MIN_PTS) ? -1 : 0;
}

extern "C" void kernel_launch(void* const* d_in, const int* in_sizes, int n_in,
                              void* d_out, int out_size, void* d_ws, size_t ws_size,
                              hipStream_t stream) {
    const float* x = (const float*)d_in[0];
    int* out = (int*)d_out;
    __bf16* aug = (__bf16*)d_ws;   // 32768 * 48 B = 1.5 MB (+16 B overread pad)

    dbscan_prep<<<dim3(Bb * Np / 256), dim3(256), 0, stream>>>(x, aug, out);
    dbscan_count<<<dim3(Bb * 32 * JS), dim3(256), 0, stream>>>(aug, out);
    dbscan_classify<<<dim3(Bb * Np / 256), dim3(256), 0, stream>>>(out);
}